// Round 1
// baseline (67.951 us; speedup 1.0000x reference)
//
#include <hip/hip_runtime.h>
#include <float.h>

#define BATCH 32
#define SEQ 2048
#define NTOT (BATCH * SEQ)
#define EPS 1e-8f

// ---- workspace layout (indexed as 4-byte words from d_ws) ----
// int   [0..31]   pred_len
// int   [32..63]  mz_len
// float [64..95]  soft_intersect per batch
// float [96]      sum sq diff mz
// float [97]      sum sq diff intensity
// float [98]      sum |sign diff| mz
// float [99]      sum |sign diff| intensity
// uint  [100]     max |mz| bits
// uint  [101]     max |intensity| bits
#define WS_PLEN 0
#define WS_MLEN 32
#define WS_SI 64
#define WS_SSD_MZ 96
#define WS_SSD_INT 97
#define WS_SGN_MZ 98
#define WS_SGN_INT 99
#define WS_MAX_MZ 100
#define WS_MAX_INT 101
#define WS_WORDS 102

__device__ inline float waveSum(float v) {
    #pragma unroll
    for (int off = 32; off; off >>= 1) v += __shfl_xor(v, off);
    return v;
}
__device__ inline float waveMax(float v) {
    #pragma unroll
    for (int off = 32; off; off >>= 1) v = fmaxf(v, __shfl_xor(v, off));
    return v;
}
__device__ inline int waveMaxI(int v) {
    #pragma unroll
    for (int off = 32; off; off >>= 1) v = max(v, __shfl_xor(v, off));
    return v;
}
__device__ inline float fsign(float x) {
    return (x > 0.0f) ? 1.0f : ((x < 0.0f) ? -1.0f : 0.0f);
}

// ---- zero the accumulator words ----
__global__ void k_zero(unsigned* ws) {
    int i = threadIdx.x;
    if (i < WS_WORDS) ws[i] = 0u;
}

// ---- row lengths: index of last negative element (0 if none) ----
// grid: 64 blocks (0..31 -> pred_mz rows, 32..63 -> mz rows), 256 threads
__global__ void k_lens(const float* __restrict__ pred_mz,
                       const float* __restrict__ mz,
                       int* __restrict__ ws_i) {
    int b = blockIdx.x;
    const float* row = (b < BATCH) ? (pred_mz + (size_t)b * SEQ)
                                   : (mz + (size_t)(b - BATCH) * SEQ);
    int lmax = 0;
    for (int i = threadIdx.x; i < SEQ; i += blockDim.x) {
        if (row[i] < 0.0f) lmax = max(lmax, i);
    }
    lmax = waveMaxI(lmax);
    __shared__ int smax[4];
    int wid = threadIdx.x >> 6;
    if ((threadIdx.x & 63) == 0) smax[wid] = lmax;
    __syncthreads();
    if (threadIdx.x == 0) {
        int m = smax[0];
        m = max(m, smax[1]); m = max(m, smax[2]); m = max(m, smax[3]);
        ws_i[b] = m;   // b<32 -> WS_PLEN+b ; else WS_MLEN+(b-32)
    }
}

// ---- fused MSE sums, sign-penalty sums, global |max| reductions ----
// grid: 256 blocks x 256 threads = exactly NTOT threads
__global__ void k_stats(const float* __restrict__ pmz,
                        const float* __restrict__ mz,
                        const float* __restrict__ inten,
                        const float* __restrict__ pint,
                        float* __restrict__ wf,
                        unsigned* __restrict__ wu) {
    float ssd_mz = 0.f, ssd_in = 0.f, sgn_mz = 0.f, sgn_in = 0.f;
    float amz = 0.f, ain = 0.f;
    for (int i = blockIdx.x * blockDim.x + threadIdx.x; i < NTOT;
         i += gridDim.x * blockDim.x) {
        float a = pmz[i], b = mz[i], c = pint[i], d = inten[i];
        float dm = a - b;  ssd_mz += dm * dm;
        float di = c - d;  ssd_in += di * di;
        sgn_mz += fabsf(fsign(a) - fsign(b));
        sgn_in += fabsf(fsign(c) - fsign(d));
        amz = fmaxf(amz, fabsf(b));
        ain = fmaxf(ain, fabsf(d));
    }
    ssd_mz = waveSum(ssd_mz); ssd_in = waveSum(ssd_in);
    sgn_mz = waveSum(sgn_mz); sgn_in = waveSum(sgn_in);
    amz = waveMax(amz); ain = waveMax(ain);

    __shared__ float sh[6][4];
    int wid = threadIdx.x >> 6;
    if ((threadIdx.x & 63) == 0) {
        sh[0][wid] = ssd_mz; sh[1][wid] = ssd_in;
        sh[2][wid] = sgn_mz; sh[3][wid] = sgn_in;
        sh[4][wid] = amz;    sh[5][wid] = ain;
    }
    __syncthreads();
    if (threadIdx.x == 0) {
        float v0 = sh[0][0] + sh[0][1] + sh[0][2] + sh[0][3];
        float v1 = sh[1][0] + sh[1][1] + sh[1][2] + sh[1][3];
        float v2 = sh[2][0] + sh[2][1] + sh[2][2] + sh[2][3];
        float v3 = sh[3][0] + sh[3][1] + sh[3][2] + sh[3][3];
        float m0 = fmaxf(fmaxf(sh[4][0], sh[4][1]), fmaxf(sh[4][2], sh[4][3]));
        float m1 = fmaxf(fmaxf(sh[5][0], sh[5][1]), fmaxf(sh[5][2], sh[5][3]));
        atomicAdd(&wf[WS_SSD_MZ], v0);
        atomicAdd(&wf[WS_SSD_INT], v1);
        atomicAdd(&wf[WS_SGN_MZ], v2);
        atomicAdd(&wf[WS_SGN_INT], v3);
        atomicMax(&wu[WS_MAX_MZ], __float_as_uint(m0));   // nonneg floats: uint order ok
        atomicMax(&wu[WS_MAX_INT], __float_as_uint(m1));
    }
}

// ---- soft Jaccard intersect: min|diff| over valid mz, exp, weight, sum ----
// grid: (BATCH, SEQ/256), block 256
__global__ __launch_bounds__(256)
void k_softjac(const float* __restrict__ pmz,
               const float* __restrict__ mz,
               const float* __restrict__ pint,
               const int* __restrict__ wi,
               float* __restrict__ wf) {
    int b = blockIdx.x;
    __shared__ float mzs[SEQ];
    int mlen = wi[WS_MLEN + b];
    int plen = wi[WS_PLEN + b];
    for (int j = threadIdx.x; j < SEQ; j += blockDim.x)
        mzs[j] = mz[(size_t)b * SEQ + j];
    __syncthreads();

    int i = blockIdx.y * blockDim.x + threadIdx.x;
    float contrib = 0.0f;
    if (i < plen && mlen > 0) {
        float a = pmz[(size_t)b * SEQ + i];
        float m0 = FLT_MAX, m1 = FLT_MAX, m2 = FLT_MAX, m3 = FLT_MAX;
        int j = 0;
        for (; j + 4 <= mlen; j += 4) {
            m0 = fminf(m0, fabsf(a - mzs[j]));
            m1 = fminf(m1, fabsf(a - mzs[j + 1]));
            m2 = fminf(m2, fabsf(a - mzs[j + 2]));
            m3 = fminf(m3, fabsf(a - mzs[j + 3]));
        }
        for (; j < mlen; ++j) m0 = fminf(m0, fabsf(a - mzs[j]));
        float mind = fminf(fminf(m0, m1), fminf(m2, m3));
        contrib = __expf(-2.0f * mind) * pint[(size_t)b * SEQ + i];
    }
    contrib = waveSum(contrib);
    __shared__ float sh[4];
    int wid = threadIdx.x >> 6;
    if ((threadIdx.x & 63) == 0) sh[wid] = contrib;
    __syncthreads();
    if (threadIdx.x == 0) {
        atomicAdd(&wf[WS_SI + b], sh[0] + sh[1] + sh[2] + sh[3]);
    }
}

// ---- finalize the four outputs ----
__global__ void k_final(const int* __restrict__ wi,
                        const float* __restrict__ wf,
                        const unsigned* __restrict__ wu,
                        float* __restrict__ out) {
    int lane = threadIdx.x;   // single wave of 64
    float t = 0.0f;
    if (lane < BATCH) {
        float si = wf[WS_SI + lane];
        float su = (float)(wi[WS_PLEN + lane] + wi[WS_MLEN + lane]);
        t = 1.0f - (si + EPS) / (su + EPS);
    }
    t = waveSum(t);
    if (lane == 0) {
        float mmz = __uint_as_float(wu[WS_MAX_MZ]);
        float mit = __uint_as_float(wu[WS_MAX_INT]);
        out[0] = t / (float)BATCH;                                   // SJ_W * sj_loss
        out[1] = (wf[WS_SSD_MZ] / (float)NTOT) / (mmz * mmz);        // MSE_MZ_W * loss_mz
        out[2] = (wf[WS_SSD_INT] / (float)NTOT) / (mit * mit);       // MSE_INT_W * loss_int
        out[3] = 0.1f * 0.5f * (wf[WS_SGN_MZ] + wf[WS_SGN_INT]) / (float)NTOT;
    }
}

extern "C" void kernel_launch(void* const* d_in, const int* in_sizes, int n_in,
                              void* d_out, int out_size, void* d_ws, size_t ws_size,
                              hipStream_t stream) {
    const float* pred_mz = (const float*)d_in[0];
    const float* mz      = (const float*)d_in[1];
    const float* inten   = (const float*)d_in[2];
    const float* pint    = (const float*)d_in[3];
    float* out = (float*)d_out;

    int*      wi = (int*)d_ws;
    float*    wf = (float*)d_ws;
    unsigned* wu = (unsigned*)d_ws;

    k_zero<<<1, 128, 0, stream>>>(wu);
    k_lens<<<64, 256, 0, stream>>>(pred_mz, mz, wi);
    k_stats<<<256, 256, 0, stream>>>(pred_mz, mz, inten, pint, wf, wu);
    k_softjac<<<dim3(BATCH, SEQ / 256), 256, 0, stream>>>(pred_mz, mz, pint, wi, wf);
    k_final<<<1, 64, 0, stream>>>(wi, wf, wu, out);
}

// Round 2
// 25.553 us; speedup vs baseline: 2.6592x; 2.6592x over previous
//
#include <hip/hip_runtime.h>
#include <float.h>

#define BATCH 32
#define SEQ 2048
#define NTOT (BATCH * SEQ)
#define EPS 1e-8f
#define CHUNKS 8
#define BLK 256
#define PADV 1e30f

// ---- ws layout (4-byte words) ---- all plain overwrites, no atomics, no zeroing
#define WS_SJ    0      // float [256]  per-block soft-intersect partial
#define WS_SSDM  256    // float [256]  sum (pmz-mz)^2 partial
#define WS_SSDI  512    // float [256]  sum (pint-int)^2 partial
#define WS_SGNM  768    // float [256]  sum |sign(pmz)-sign(mz)| partial
#define WS_SGNI  1024   // float [256]  sum |sign(pint)-sign(int)| partial
#define WS_AMZ   1280   // float [256]  max |mz| partial
#define WS_AIN   1536   // float [256]  max |int| partial
#define WS_PLEN  1792   // int   [32]
#define WS_MLEN  1824   // int   [32]

__device__ inline float waveSum(float v) {
    #pragma unroll
    for (int off = 32; off; off >>= 1) v += __shfl_xor(v, off);
    return v;
}
__device__ inline float waveMax(float v) {
    #pragma unroll
    for (int off = 32; off; off >>= 1) v = fmaxf(v, __shfl_xor(v, off));
    return v;
}
__device__ inline int waveMaxI(int v) {
    #pragma unroll
    for (int off = 32; off; off >>= 1) v = max(v, __shfl_xor(v, off));
    return v;
}
__device__ inline float fsign(float x) {
    return (x > 0.0f) ? 1.0f : ((x < 0.0f) ? -1.0f : 0.0f);
}

// ==== fused main kernel: grid (BATCH, CHUNKS) x BLK ====
// block (b,c): owns elements idx = b*SEQ + c*BLK + t  (one per thread) for the
// stats partials, and pred elements i = c*BLK + t for soft-Jaccard.
__global__ __launch_bounds__(BLK)
void k_main(const float* __restrict__ pmz,  const float* __restrict__ mz,
            const float* __restrict__ inten, const float* __restrict__ pint,
            float* __restrict__ wf, int* __restrict__ wi) {
    const int b = blockIdx.x;
    const int c = blockIdx.y;
    const int t = threadIdx.x;
    const int wid = t >> 6;

    __shared__ float mzs[SEQ];
    __shared__ int   smP[4], smM[4];
    __shared__ float red[7][4];

    const float* mzrow = mz  + (size_t)b * SEQ;
    const float* prow  = pmz + (size_t)b * SEQ;

    // stage full mz row to LDS (each thread 8 contiguous floats), and scan
    // both rows for the last-negative index while the data is in registers
    const int base = t * 8;
    float4 mv0 = *(const float4*)(mzrow + base);
    float4 mv1 = *(const float4*)(mzrow + base + 4);
    float4 pv0 = *(const float4*)(prow  + base);
    float4 pv1 = *(const float4*)(prow  + base + 4);
    *(float4*)(mzs + base)     = mv0;
    *(float4*)(mzs + base + 4) = mv1;

    int lm = 0, lp = 0;   // ascending overwrite == max index with value<0
    if (mv0.x < 0.f) lm = base + 0;  if (mv0.y < 0.f) lm = base + 1;
    if (mv0.z < 0.f) lm = base + 2;  if (mv0.w < 0.f) lm = base + 3;
    if (mv1.x < 0.f) lm = base + 4;  if (mv1.y < 0.f) lm = base + 5;
    if (mv1.z < 0.f) lm = base + 6;  if (mv1.w < 0.f) lm = base + 7;
    if (pv0.x < 0.f) lp = base + 0;  if (pv0.y < 0.f) lp = base + 1;
    if (pv0.z < 0.f) lp = base + 2;  if (pv0.w < 0.f) lp = base + 3;
    if (pv1.x < 0.f) lp = base + 4;  if (pv1.y < 0.f) lp = base + 5;
    if (pv1.z < 0.f) lp = base + 6;  if (pv1.w < 0.f) lp = base + 7;
    lm = waveMaxI(lm);  lp = waveMaxI(lp);
    if ((t & 63) == 0) { smM[wid] = lm; smP[wid] = lp; }
    __syncthreads();
    const int mlen = max(max(smM[0], smM[1]), max(smM[2], smM[3]));
    const int plen = max(max(smP[0], smP[1]), max(smP[2], smP[3]));

    // pad invalid mz tail with a huge value: min|diff| -> ~1e30 -> exp -> 0,
    // which also handles mlen == 0 with no special case
    #pragma unroll
    for (int k = 0; k < 8; ++k)
        if (base + k >= mlen) mzs[base + k] = PADV;
    __syncthreads();

    // per-thread element for stats + soft-jaccard
    const int i   = c * BLK + t;
    const size_t idx = (size_t)b * SEQ + i;
    const float a   = prow[i];        // L1-hot (whole row just streamed)
    const float bm  = mzrow[i];       // L1-hot
    const float ci  = pint[idx];
    const float di  = inten[idx];

    float dm = a - bm;
    float dd = ci - di;
    float ssd_m = dm * dm;
    float ssd_i = dd * dd;
    float sgn_m = fabsf(fsign(a)  - fsign(bm));
    float sgn_i = fabsf(fsign(ci) - fsign(di));
    float amz   = fabsf(bm);
    float ain   = fabsf(di);

    // min |a - mz[j]| over the (padded) row — 4 independent chains, b128 reads
    float m0 = PADV, m1 = PADV, m2 = PADV, m3 = PADV;
    const float4* m4 = (const float4*)mzs;
    #pragma unroll 4
    for (int j = 0; j < SEQ / 4; ++j) {
        float4 v = m4[j];
        m0 = fminf(m0, fabsf(a - v.x));
        m1 = fminf(m1, fabsf(a - v.y));
        m2 = fminf(m2, fabsf(a - v.z));
        m3 = fminf(m3, fabsf(a - v.w));
    }
    float mind = fminf(fminf(m0, m1), fminf(m2, m3));
    float contrib = (i < plen) ? __expf(-2.0f * mind) * ci : 0.0f;

    // block-reduce 7 partials
    float s0 = waveSum(contrib);
    float s1 = waveSum(ssd_m);
    float s2 = waveSum(ssd_i);
    float s3 = waveSum(sgn_m);
    float s4 = waveSum(sgn_i);
    float s5 = waveMax(amz);
    float s6 = waveMax(ain);
    if ((t & 63) == 0) {
        red[0][wid] = s0; red[1][wid] = s1; red[2][wid] = s2; red[3][wid] = s3;
        red[4][wid] = s4; red[5][wid] = s5; red[6][wid] = s6;
    }
    __syncthreads();
    if (t == 0) {
        const int bc = b * CHUNKS + c;
        wf[WS_SJ   + bc] = red[0][0] + red[0][1] + red[0][2] + red[0][3];
        wf[WS_SSDM + bc] = red[1][0] + red[1][1] + red[1][2] + red[1][3];
        wf[WS_SSDI + bc] = red[2][0] + red[2][1] + red[2][2] + red[2][3];
        wf[WS_SGNM + bc] = red[3][0] + red[3][1] + red[3][2] + red[3][3];
        wf[WS_SGNI + bc] = red[4][0] + red[4][1] + red[4][2] + red[4][3];
        wf[WS_AMZ  + bc] = fmaxf(fmaxf(red[5][0], red[5][1]), fmaxf(red[5][2], red[5][3]));
        wf[WS_AIN  + bc] = fmaxf(fmaxf(red[6][0], red[6][1]), fmaxf(red[6][2], red[6][3]));
        if (c == 0) { wi[WS_PLEN + b] = plen; wi[WS_MLEN + b] = mlen; }
    }
}

// ==== finalize: 1 block x 256 threads ====
__global__ __launch_bounds__(BLK)
void k_final(const float* __restrict__ wf, const int* __restrict__ wi,
             float* __restrict__ out) {
    const int t = threadIdx.x;
    const int wid = t >> 6;
    __shared__ float terms[BATCH];
    __shared__ float red[6][4];

    // soft-jaccard: t = b*8 + c ; sum the 8 chunk partials per batch
    float sj = wf[WS_SJ + t];
    #pragma unroll
    for (int off = 1; off < CHUNKS; off <<= 1) sj += __shfl_xor(sj, off);
    if ((t & 7) == 0) {
        int b = t >> 3;
        float su = (float)(wi[WS_PLEN + b] + wi[WS_MLEN + b]);
        terms[b] = 1.0f - (sj + EPS) / (su + EPS);
    }

    // stats partial combine
    float v1 = wf[WS_SSDM + t];
    float v2 = wf[WS_SSDI + t];
    float v3 = wf[WS_SGNM + t];
    float v4 = wf[WS_SGNI + t];
    float v5 = wf[WS_AMZ + t];
    float v6 = wf[WS_AIN + t];
    v1 = waveSum(v1); v2 = waveSum(v2); v3 = waveSum(v3); v4 = waveSum(v4);
    v5 = waveMax(v5); v6 = waveMax(v6);
    if ((t & 63) == 0) {
        red[0][wid] = v1; red[1][wid] = v2; red[2][wid] = v3;
        red[3][wid] = v4; red[4][wid] = v5; red[5][wid] = v6;
    }
    __syncthreads();

    // wave 0: sum the 32 batch terms
    float term = (t < BATCH) ? terms[t] : 0.0f;
    if (t < 64) term = waveSum(term);

    if (t == 0) {
        float ssd_m = red[0][0] + red[0][1] + red[0][2] + red[0][3];
        float ssd_i = red[1][0] + red[1][1] + red[1][2] + red[1][3];
        float sgn_m = red[2][0] + red[2][1] + red[2][2] + red[2][3];
        float sgn_i = red[3][0] + red[3][1] + red[3][2] + red[3][3];
        float amz = fmaxf(fmaxf(red[4][0], red[4][1]), fmaxf(red[4][2], red[4][3]));
        float ain = fmaxf(fmaxf(red[5][0], red[5][1]), fmaxf(red[5][2], red[5][3]));
        out[0] = term / (float)BATCH;
        out[1] = (ssd_m / (float)NTOT) / (amz * amz);
        out[2] = (ssd_i / (float)NTOT) / (ain * ain);
        out[3] = 0.1f * 0.5f * (sgn_m + sgn_i) / (float)NTOT;
    }
}

extern "C" void kernel_launch(void* const* d_in, const int* in_sizes, int n_in,
                              void* d_out, int out_size, void* d_ws, size_t ws_size,
                              hipStream_t stream) {
    const float* pred_mz = (const float*)d_in[0];
    const float* mz      = (const float*)d_in[1];
    const float* inten   = (const float*)d_in[2];
    const float* pint    = (const float*)d_in[3];
    float* out = (float*)d_out;
    float* wf = (float*)d_ws;
    int*   wi = (int*)d_ws;

    k_main<<<dim3(BATCH, CHUNKS), BLK, 0, stream>>>(pred_mz, mz, inten, pint, wf, wi);
    k_final<<<1, BLK, 0, stream>>>(wf, wi, out);
}

// Round 3
// 17.484 us; speedup vs baseline: 3.8864x; 1.4615x over previous
//
#include <hip/hip_runtime.h>

#define BATCH 32
#define SEQ 2048
#define NTOT (BATCH * SEQ)
#define EPS 1e-8f
#define BLK 256
#define SEGS 4
#define SEGLEN (SEQ / SEGS)       // 512 floats per segment
#define LDSSEG (SEGLEN + 4)       // +4-word pad -> segment bases hit distinct banks
#define CBLK 64                   // pred elements per block
#define NCH (SEQ / CBLK)          // 32 chunks per batch row
#define NPART (BATCH * NCH)       // 1024 per-block partials
#define PADV 1e30f

// ---- ws layout (4-byte words) ---- all plain overwrites, no atomics, no zeroing
#define WS_SJ    0                // float [1024]
#define WS_SSDM  (NPART)          // float [1024]
#define WS_SSDI  (2 * NPART)
#define WS_SGNM  (3 * NPART)
#define WS_SGNI  (4 * NPART)
#define WS_AMZ   (5 * NPART)
#define WS_AIN   (6 * NPART)
#define WS_PLEN  (7 * NPART)      // int [32]
#define WS_MLEN  (7 * NPART + 32) // int [32]

__device__ inline float waveSum(float v) {
    #pragma unroll
    for (int off = 32; off; off >>= 1) v += __shfl_xor(v, off);
    return v;
}
__device__ inline float waveMax(float v) {
    #pragma unroll
    for (int off = 32; off; off >>= 1) v = fmaxf(v, __shfl_xor(v, off));
    return v;
}
__device__ inline int waveMaxI(int v) {
    #pragma unroll
    for (int off = 32; off; off >>= 1) v = max(v, __shfl_xor(v, off));
    return v;
}
__device__ inline float fsign(float x) {
    return (x > 0.0f) ? 1.0f : ((x < 0.0f) ? -1.0f : 0.0f);
}

// ==== fused main kernel: grid (BATCH, NCH) x BLK ====
// Block (b,c) owns 64 pred elements; each element is scanned by 4 lanes,
// one per 512-float mz segment (4x thread-level parallelism vs round 2).
__global__ __launch_bounds__(BLK)
void k_main(const float* __restrict__ pmz,  const float* __restrict__ mz,
            const float* __restrict__ inten, const float* __restrict__ pint,
            float* __restrict__ wf, int* __restrict__ wi) {
    const int b = blockIdx.x;
    const int c = blockIdx.y;
    const int t = threadIdx.x;
    const int wid = t >> 6;

    __shared__ float mzs[SEGS * LDSSEG];
    __shared__ int   smP[4], smM[4];
    __shared__ float red[7][4];

    const float* mzrow = mz  + (size_t)b * SEQ;
    const float* prow  = pmz + (size_t)b * SEQ;

    // ---- stage mz row to LDS (seg-padded) + last-negative scans ----
    const int base  = t * 8;                    // global word index in row
    const int lbase = base + ((t >> 6) << 2);   // +4 words per segment
    float4 mv0 = *(const float4*)(mzrow + base);
    float4 mv1 = *(const float4*)(mzrow + base + 4);
    float4 pv0 = *(const float4*)(prow  + base);
    float4 pv1 = *(const float4*)(prow  + base + 4);
    *(float4*)(mzs + lbase)     = mv0;
    *(float4*)(mzs + lbase + 4) = mv1;

    int lm = 0, lp = 0;   // ascending overwrite == index of last negative
    if (mv0.x < 0.f) lm = base + 0;  if (mv0.y < 0.f) lm = base + 1;
    if (mv0.z < 0.f) lm = base + 2;  if (mv0.w < 0.f) lm = base + 3;
    if (mv1.x < 0.f) lm = base + 4;  if (mv1.y < 0.f) lm = base + 5;
    if (mv1.z < 0.f) lm = base + 6;  if (mv1.w < 0.f) lm = base + 7;
    if (pv0.x < 0.f) lp = base + 0;  if (pv0.y < 0.f) lp = base + 1;
    if (pv0.z < 0.f) lp = base + 2;  if (pv0.w < 0.f) lp = base + 3;
    if (pv1.x < 0.f) lp = base + 4;  if (pv1.y < 0.f) lp = base + 5;
    if (pv1.z < 0.f) lp = base + 6;  if (pv1.w < 0.f) lp = base + 7;
    lm = waveMaxI(lm);  lp = waveMaxI(lp);
    if ((t & 63) == 0) { smM[wid] = lm; smP[wid] = lp; }
    __syncthreads();
    const int mlen = max(max(smM[0], smM[1]), max(smM[2], smM[3]));
    const int plen = max(max(smP[0], smP[1]), max(smP[2], smP[3]));

    // pad invalid tail with huge value: min -> ~1e30 -> exp -> 0 (handles mlen==0 too)
    #pragma unroll
    for (int k = 0; k < 8; ++k)
        if (base + k >= mlen) mzs[lbase + k] = PADV;
    __syncthreads();

    // ---- 4-way split min-scan: lane (il, s) scans segment s for pred elem il ----
    const int il = t >> 2;          // 0..63
    const int s  = t & 3;           // segment id
    const int i  = c * CBLK + il;   // pred element index in row
    const float a = prow[i];        // L1-hot broadcast (4 lanes share)

    const float4* seg = (const float4*)(mzs + s * LDSSEG);
    float m0 = PADV, m1 = PADV;
    #pragma unroll 8
    for (int j = 0; j < SEGLEN / 4; ++j) {
        float4 v = seg[j];
        float d0 = a - v.x, d1 = a - v.y, d2 = a - v.z, d3 = a - v.w;
        m0 = fminf(m0, fminf(fabsf(d0), fabsf(d1)));   // -> v_min3 with |.| mods
        m1 = fminf(m1, fminf(fabsf(d2), fabsf(d3)));
    }
    float m = fminf(m0, m1);
    m = fminf(m, __shfl_xor(m, 1));   // combine the 4 segment minima
    m = fminf(m, __shfl_xor(m, 2));

    // ---- stats + contribution on the s==0 lane of each element ----
    float contrib = 0.f, ssd_m = 0.f, ssd_i = 0.f, sgn_m = 0.f, sgn_i = 0.f;
    float amz = 0.f, ain = 0.f;
    if (s == 0) {
        const size_t idx = (size_t)b * SEQ + i;
        const float bm = mzrow[i];
        const float ci = pint[idx];
        const float di = inten[idx];
        float dm = a - bm;   ssd_m = dm * dm;
        float dd = ci - di;  ssd_i = dd * dd;
        sgn_m = fabsf(fsign(a)  - fsign(bm));
        sgn_i = fabsf(fsign(ci) - fsign(di));
        amz = fabsf(bm);
        ain = fabsf(di);
        contrib = (i < plen) ? __expf(-2.0f * m) * ci : 0.0f;
    }

    // ---- block-reduce 7 partials ----
    float s0 = waveSum(contrib);
    float s1 = waveSum(ssd_m);
    float s2 = waveSum(ssd_i);
    float s3 = waveSum(sgn_m);
    float s4 = waveSum(sgn_i);
    float s5 = waveMax(amz);
    float s6 = waveMax(ain);
    if ((t & 63) == 0) {
        red[0][wid] = s0; red[1][wid] = s1; red[2][wid] = s2; red[3][wid] = s3;
        red[4][wid] = s4; red[5][wid] = s5; red[6][wid] = s6;
    }
    __syncthreads();
    if (t == 0) {
        const int bc = b * NCH + c;
        wf[WS_SJ   + bc] = red[0][0] + red[0][1] + red[0][2] + red[0][3];
        wf[WS_SSDM + bc] = red[1][0] + red[1][1] + red[1][2] + red[1][3];
        wf[WS_SSDI + bc] = red[2][0] + red[2][1] + red[2][2] + red[2][3];
        wf[WS_SGNM + bc] = red[3][0] + red[3][1] + red[3][2] + red[3][3];
        wf[WS_SGNI + bc] = red[4][0] + red[4][1] + red[4][2] + red[4][3];
        wf[WS_AMZ  + bc] = fmaxf(fmaxf(red[5][0], red[5][1]), fmaxf(red[5][2], red[5][3]));
        wf[WS_AIN  + bc] = fmaxf(fmaxf(red[6][0], red[6][1]), fmaxf(red[6][2], red[6][3]));
        if (c == 0) { wi[WS_PLEN + b] = plen; wi[WS_MLEN + b] = mlen; }
    }
}

// ==== finalize: 1 block x 256 threads, 1024 partials per array ====
__global__ __launch_bounds__(BLK)
void k_final(const float* __restrict__ wf, const int* __restrict__ wi,
             float* __restrict__ out) {
    const int t = threadIdx.x;
    const int wid = t >> 6;
    __shared__ float terms[BATCH];
    __shared__ float red[6][4];

    // soft-jaccard: partial p = b*32 + c; thread t holds p = 4t..4t+3 (one batch),
    // 8-lane group covers one batch of 32 partials
    float4 v = *(const float4*)(wf + WS_SJ + 4 * t);
    float sj = v.x + v.y + v.z + v.w;
    sj += __shfl_xor(sj, 1);
    sj += __shfl_xor(sj, 2);
    sj += __shfl_xor(sj, 4);
    if ((t & 7) == 0) {
        int b = t >> 3;
        float su = (float)(wi[WS_PLEN + b] + wi[WS_MLEN + b]);
        terms[b] = 1.0f - (sj + EPS) / (su + EPS);
    }

    // stats partial combine (float4 per thread, then block reduce)
    float4 q1 = *(const float4*)(wf + WS_SSDM + 4 * t);
    float4 q2 = *(const float4*)(wf + WS_SSDI + 4 * t);
    float4 q3 = *(const float4*)(wf + WS_SGNM + 4 * t);
    float4 q4 = *(const float4*)(wf + WS_SGNI + 4 * t);
    float4 q5 = *(const float4*)(wf + WS_AMZ  + 4 * t);
    float4 q6 = *(const float4*)(wf + WS_AIN  + 4 * t);
    float v1 = q1.x + q1.y + q1.z + q1.w;
    float v2 = q2.x + q2.y + q2.z + q2.w;
    float v3 = q3.x + q3.y + q3.z + q3.w;
    float v4 = q4.x + q4.y + q4.z + q4.w;
    float v5 = fmaxf(fmaxf(q5.x, q5.y), fmaxf(q5.z, q5.w));
    float v6 = fmaxf(fmaxf(q6.x, q6.y), fmaxf(q6.z, q6.w));
    v1 = waveSum(v1); v2 = waveSum(v2); v3 = waveSum(v3); v4 = waveSum(v4);
    v5 = waveMax(v5); v6 = waveMax(v6);
    if ((t & 63) == 0) {
        red[0][wid] = v1; red[1][wid] = v2; red[2][wid] = v3;
        red[3][wid] = v4; red[4][wid] = v5; red[5][wid] = v6;
    }
    __syncthreads();

    // wave 0: sum the 32 batch terms
    float term = (t < BATCH) ? terms[t] : 0.0f;
    if (t < 64) term = waveSum(term);

    if (t == 0) {
        float ssd_m = red[0][0] + red[0][1] + red[0][2] + red[0][3];
        float ssd_i = red[1][0] + red[1][1] + red[1][2] + red[1][3];
        float sgn_m = red[2][0] + red[2][1] + red[2][2] + red[2][3];
        float sgn_i = red[3][0] + red[3][1] + red[3][2] + red[3][3];
        float amz = fmaxf(fmaxf(red[4][0], red[4][1]), fmaxf(red[4][2], red[4][3]));
        float ain = fmaxf(fmaxf(red[5][0], red[5][1]), fmaxf(red[5][2], red[5][3]));
        out[0] = term / (float)BATCH;
        out[1] = (ssd_m / (float)NTOT) / (amz * amz);
        out[2] = (ssd_i / (float)NTOT) / (ain * ain);
        out[3] = 0.1f * 0.5f * (sgn_m + sgn_i) / (float)NTOT;
    }
}

extern "C" void kernel_launch(void* const* d_in, const int* in_sizes, int n_in,
                              void* d_out, int out_size, void* d_ws, size_t ws_size,
                              hipStream_t stream) {
    const float* pred_mz = (const float*)d_in[0];
    const float* mz      = (const float*)d_in[1];
    const float* inten   = (const float*)d_in[2];
    const float* pint    = (const float*)d_in[3];
    float* out = (float*)d_out;
    float* wf = (float*)d_ws;
    int*   wi = (int*)d_ws;

    k_main<<<dim3(BATCH, NCH), BLK, 0, stream>>>(pred_mz, mz, inten, pint, wf, wi);
    k_final<<<1, BLK, 0, stream>>>(wf, wi, out);
}

// Round 4
// 16.044 us; speedup vs baseline: 4.2354x; 1.0898x over previous
//
#include <hip/hip_runtime.h>

#define BATCH 32
#define SEQ 2048
#define NTOT (BATCH * SEQ)
#define EPS 1e-8f
#define BLK 256
#define SEGS 16
#define SEGLEN (SEQ / SEGS)       // 128 floats per segment
#define LDSW (SEGLEN + 4)         // +4-word pad -> 2-way bank aliasing only
#define E 8                       // pred elements per thread (register-blocked)
#define GRP (BLK / SEGS)          // 16 pred groups per block
#define CBLK (GRP * E)            // 128 pred elements per block
#define NCH (SEQ / CBLK)          // 16 chunks per batch row
#define NPART (BATCH * NCH)       // 512 per-block partials
#define PADV 1e30f

// ---- ws layout (4-byte words) ---- plain overwrites only, no atomics/zeroing
#define WS_SJ    0
#define WS_SSDM  (NPART)
#define WS_SSDI  (2 * NPART)
#define WS_SGNM  (3 * NPART)
#define WS_SGNI  (4 * NPART)
#define WS_AMZ   (5 * NPART)
#define WS_AIN   (6 * NPART)
#define WS_PLEN  (7 * NPART)       // int [32]
#define WS_MLEN  (7 * NPART + 32)  // int [32]

__device__ inline float waveSum(float v) {
    #pragma unroll
    for (int off = 32; off; off >>= 1) v += __shfl_xor(v, off);
    return v;
}
__device__ inline float waveMax(float v) {
    #pragma unroll
    for (int off = 32; off; off >>= 1) v = fmaxf(v, __shfl_xor(v, off));
    return v;
}
__device__ inline int waveMaxI(int v) {
    #pragma unroll
    for (int off = 32; off; off >>= 1) v = max(v, __shfl_xor(v, off));
    return v;
}
__device__ inline float fsign(float x) {
    return (x > 0.0f) ? 1.0f : ((x < 0.0f) ? -1.0f : 0.0f);
}

// ==== fused main kernel: grid (BATCH, NCH) x BLK ====
// Thread t = ig*SEGS + s: holds E=8 pred elements (group ig) in registers and
// scans mz segment s (128 floats) from LDS; each ds_read_b128 feeds 8 preds.
__global__ __launch_bounds__(BLK)
void k_main(const float* __restrict__ pmz,  const float* __restrict__ mz,
            const float* __restrict__ inten, const float* __restrict__ pint,
            float* __restrict__ wf, int* __restrict__ wi) {
    const int b = blockIdx.x;
    const int c = blockIdx.y;
    const int t = threadIdx.x;
    const int wid = t >> 6;

    __shared__ float mzs[SEGS * LDSW];
    __shared__ int   smP[4], smM[4];
    __shared__ float red[7][4];

    const float* mzrow = mz  + (size_t)b * SEQ;
    const float* prow  = pmz + (size_t)b * SEQ;

    // ---- stage mz row to LDS (segment-padded) + last-negative scans ----
    const int base  = t * 8;                        // word index in row
    const int lbase = base + ((base >> 7) << 2);    // +4 words per 128-word seg
    float4 mv0 = *(const float4*)(mzrow + base);
    float4 mv1 = *(const float4*)(mzrow + base + 4);
    float4 pv0 = *(const float4*)(prow  + base);
    float4 pv1 = *(const float4*)(prow  + base + 4);
    *(float4*)(mzs + lbase)     = mv0;
    *(float4*)(mzs + lbase + 4) = mv1;

    int lm = 0, lp = 0;   // ascending overwrite == index of last negative
    if (mv0.x < 0.f) lm = base + 0;  if (mv0.y < 0.f) lm = base + 1;
    if (mv0.z < 0.f) lm = base + 2;  if (mv0.w < 0.f) lm = base + 3;
    if (mv1.x < 0.f) lm = base + 4;  if (mv1.y < 0.f) lm = base + 5;
    if (mv1.z < 0.f) lm = base + 6;  if (mv1.w < 0.f) lm = base + 7;
    if (pv0.x < 0.f) lp = base + 0;  if (pv0.y < 0.f) lp = base + 1;
    if (pv0.z < 0.f) lp = base + 2;  if (pv0.w < 0.f) lp = base + 3;
    if (pv1.x < 0.f) lp = base + 4;  if (pv1.y < 0.f) lp = base + 5;
    if (pv1.z < 0.f) lp = base + 6;  if (pv1.w < 0.f) lp = base + 7;
    lm = waveMaxI(lm);  lp = waveMaxI(lp);
    if ((t & 63) == 0) { smM[wid] = lm; smP[wid] = lp; }
    __syncthreads();
    const int mlen = max(max(smM[0], smM[1]), max(smM[2], smM[3]));
    const int plen = max(max(smP[0], smP[1]), max(smP[2], smP[3]));

    // pad invalid tail: min -> ~1e30 -> exp -> 0 (also handles mlen==0)
    #pragma unroll
    for (int k = 0; k < 8; ++k)
        if (base + k >= mlen) mzs[lbase + k] = PADV;
    __syncthreads();

    // ---- stats on threads t < CBLK (one element each) ----
    float ssd_m = 0.f, ssd_i = 0.f, sgn_m = 0.f, sgn_i = 0.f, amz = 0.f, ain = 0.f;
    if (t < CBLK) {
        const int i = c * CBLK + t;
        const size_t idx = (size_t)b * SEQ + i;
        const float a  = prow[i];
        const float bm = mzrow[i];
        const float ci = pint[idx];
        const float di = inten[idx];
        float dm = a - bm;   ssd_m = dm * dm;
        float dd = ci - di;  ssd_i = dd * dd;
        sgn_m = fabsf(fsign(a)  - fsign(bm));
        sgn_i = fabsf(fsign(ci) - fsign(di));
        amz = fabsf(bm);
        ain = fabsf(di);
    }

    // ---- register-blocked min-scan ----
    const int s  = t & (SEGS - 1);       // segment id
    const int ig = t >> 4;               // pred group
    const int pb = c * CBLK + ig * E;    // first pred element of this thread
    float4 pa0 = *(const float4*)(prow + pb);
    float4 pa1 = *(const float4*)(prow + pb + 4);
    float a[E] = {pa0.x, pa0.y, pa0.z, pa0.w, pa1.x, pa1.y, pa1.z, pa1.w};
    float mn[E];
    #pragma unroll
    for (int e = 0; e < E; ++e) mn[e] = PADV;

    const float4* seg4 = (const float4*)(mzs + s * LDSW);
    #pragma unroll 4
    for (int j = 0; j < SEGLEN / 4; ++j) {
        float4 v = seg4[j];
        #pragma unroll
        for (int e = 0; e < E; ++e) {
            float d0 = a[e] - v.x, d1 = a[e] - v.y;
            float d2 = a[e] - v.z, d3 = a[e] - v.w;
            mn[e] = fminf(mn[e], fminf(fabsf(d0), fabsf(d1)));  // -> v_min3 |.|
            mn[e] = fminf(mn[e], fminf(fabsf(d2), fabsf(d3)));
        }
    }
    // combine the 16 segment minima (lanes ig*16 .. ig*16+15)
    #pragma unroll
    for (int e = 0; e < E; ++e) {
        float m = mn[e];
        m = fminf(m, __shfl_xor(m, 1));
        m = fminf(m, __shfl_xor(m, 2));
        m = fminf(m, __shfl_xor(m, 4));
        m = fminf(m, __shfl_xor(m, 8));
        mn[e] = m;
    }

    // contribution: s==0 lane of each group handles its 8 preds
    float contrib = 0.0f;
    if (s == 0) {
        const float* pintrow = pint + (size_t)b * SEQ;
        float4 w0 = *(const float4*)(pintrow + pb);
        float4 w1 = *(const float4*)(pintrow + pb + 4);
        float w[E] = {w0.x, w0.y, w0.z, w0.w, w1.x, w1.y, w1.z, w1.w};
        #pragma unroll
        for (int e = 0; e < E; ++e)
            if (pb + e < plen) contrib += __expf(-2.0f * mn[e]) * w[e];
    }

    // ---- block-reduce 7 partials ----
    float s0 = waveSum(contrib);
    float s1 = waveSum(ssd_m);
    float s2 = waveSum(ssd_i);
    float s3 = waveSum(sgn_m);
    float s4 = waveSum(sgn_i);
    float s5 = waveMax(amz);
    float s6 = waveMax(ain);
    if ((t & 63) == 0) {
        red[0][wid] = s0; red[1][wid] = s1; red[2][wid] = s2; red[3][wid] = s3;
        red[4][wid] = s4; red[5][wid] = s5; red[6][wid] = s6;
    }
    __syncthreads();
    if (t == 0) {
        const int bc = b * NCH + c;
        wf[WS_SJ   + bc] = red[0][0] + red[0][1] + red[0][2] + red[0][3];
        wf[WS_SSDM + bc] = red[1][0] + red[1][1] + red[1][2] + red[1][3];
        wf[WS_SSDI + bc] = red[2][0] + red[2][1] + red[2][2] + red[2][3];
        wf[WS_SGNM + bc] = red[3][0] + red[3][1] + red[3][2] + red[3][3];
        wf[WS_SGNI + bc] = red[4][0] + red[4][1] + red[4][2] + red[4][3];
        wf[WS_AMZ  + bc] = fmaxf(fmaxf(red[5][0], red[5][1]), fmaxf(red[5][2], red[5][3]));
        wf[WS_AIN  + bc] = fmaxf(fmaxf(red[6][0], red[6][1]), fmaxf(red[6][2], red[6][3]));
        if (c == 0) { wi[WS_PLEN + b] = plen; wi[WS_MLEN + b] = mlen; }
    }
}

// ==== finalize: 1 block x 256 threads, 512 partials per array ====
__global__ __launch_bounds__(BLK)
void k_final(const float* __restrict__ wf, const int* __restrict__ wi,
             float* __restrict__ out) {
    const int t = threadIdx.x;
    const int wid = t >> 6;
    __shared__ float terms[BATCH];
    __shared__ float red[6][4];

    // soft-jaccard: batch b's 16 partials at [16b,16b+16); thread t holds 2t,2t+1
    float2 v = *(const float2*)(wf + WS_SJ + 2 * t);
    float sj = v.x + v.y;
    sj += __shfl_xor(sj, 1);
    sj += __shfl_xor(sj, 2);
    sj += __shfl_xor(sj, 4);
    if ((t & 7) == 0) {
        int bb = t >> 3;
        float su = (float)(wi[WS_PLEN + bb] + wi[WS_MLEN + bb]);
        terms[bb] = 1.0f - (sj + EPS) / (su + EPS);
    }

    // stats partial combine (float2 per thread, then block reduce)
    float2 q1 = *(const float2*)(wf + WS_SSDM + 2 * t);
    float2 q2 = *(const float2*)(wf + WS_SSDI + 2 * t);
    float2 q3 = *(const float2*)(wf + WS_SGNM + 2 * t);
    float2 q4 = *(const float2*)(wf + WS_SGNI + 2 * t);
    float2 q5 = *(const float2*)(wf + WS_AMZ  + 2 * t);
    float2 q6 = *(const float2*)(wf + WS_AIN  + 2 * t);
    float v1 = q1.x + q1.y;
    float v2 = q2.x + q2.y;
    float v3 = q3.x + q3.y;
    float v4 = q4.x + q4.y;
    float v5 = fmaxf(q5.x, q5.y);
    float v6 = fmaxf(q6.x, q6.y);
    v1 = waveSum(v1); v2 = waveSum(v2); v3 = waveSum(v3); v4 = waveSum(v4);
    v5 = waveMax(v5); v6 = waveMax(v6);
    if ((t & 63) == 0) {
        red[0][wid] = v1; red[1][wid] = v2; red[2][wid] = v3;
        red[3][wid] = v4; red[4][wid] = v5; red[5][wid] = v6;
    }
    __syncthreads();

    // wave 0: sum the 32 batch terms
    float term = (t < BATCH) ? terms[t] : 0.0f;
    if (t < 64) term = waveSum(term);

    if (t == 0) {
        float ssd_m = red[0][0] + red[0][1] + red[0][2] + red[0][3];
        float ssd_i = red[1][0] + red[1][1] + red[1][2] + red[1][3];
        float sgn_m = red[2][0] + red[2][1] + red[2][2] + red[2][3];
        float sgn_i = red[3][0] + red[3][1] + red[3][2] + red[3][3];
        float amz = fmaxf(fmaxf(red[4][0], red[4][1]), fmaxf(red[4][2], red[4][3]));
        float ain = fmaxf(fmaxf(red[5][0], red[5][1]), fmaxf(red[5][2], red[5][3]));
        out[0] = term / (float)BATCH;
        out[1] = (ssd_m / (float)NTOT) / (amz * amz);
        out[2] = (ssd_i / (float)NTOT) / (ain * ain);
        out[3] = 0.1f * 0.5f * (sgn_m + sgn_i) / (float)NTOT;
    }
}

extern "C" void kernel_launch(void* const* d_in, const int* in_sizes, int n_in,
                              void* d_out, int out_size, void* d_ws, size_t ws_size,
                              hipStream_t stream) {
    const float* pred_mz = (const float*)d_in[0];
    const float* mz      = (const float*)d_in[1];
    const float* inten   = (const float*)d_in[2];
    const float* pint    = (const float*)d_in[3];
    float* out = (float*)d_out;
    float* wf = (float*)d_ws;
    int*   wi = (int*)d_ws;

    k_main<<<dim3(BATCH, NCH), BLK, 0, stream>>>(pred_mz, mz, inten, pint, wf, wi);
    k_final<<<1, BLK, 0, stream>>>(wf, wi, out);
}